// Round 2
// baseline (199.110 us; speedup 1.0000x reference)
//
#include <hip/hip_runtime.h>
#include <math.h>

#define NN 8192
#define EPSF 1e-6f

// ws layout:
//   pack[NN]  : float4 {T[j], exp(Pr[j]), E[j]*exp(Ps[j]), 0}   (131072 B)
//   sumR[NN]  : float                                            (32768 B)
//   sumS[NN]  : float                                            (32768 B)
//   ticket    : unsigned int                                     (4 B)
// total ~196612 B  (ws re-poisoned 0xAA each call -> prep zeroes sums+ticket)

__global__ __launch_bounds__(256) void ds_prep(
    const float* __restrict__ Pr, const float* __restrict__ Ps,
    const float* __restrict__ T,  const int* __restrict__ E,
    float4* __restrict__ pack, float* __restrict__ sumR, float* __restrict__ sumS,
    unsigned int* __restrict__ ticket) {
  int i = blockIdx.x * 256 + threadIdx.x;
  float t  = T[i];
  float er = __expf(Pr[i]);
  float es = E[i] ? __expf(Ps[i]) : 0.0f;
  pack[i] = make_float4(t, er, es, 0.0f);
  sumR[i] = 0.0f;
  sumS[i] = 0.0f;
  if (i == 0) *ticket = 0u;
}

// Main pass: block = 64 rows x 4 j-stripes (256 threads, stripe==wave so the
// pack[j] address is wave-uniform -> s_load). Grid (128 row-blocks, 16 chunks
// of 512 j). Last block (ticket) finalizes the two scalar losses.
#define GX 128
#define GY 16
#define STRIPE 128   // j per thread = 512 chunk / 4 stripes

__global__ __launch_bounds__(256) void ds_main(
    const float* __restrict__ T, const float4* __restrict__ pack,
    const float* __restrict__ Pr, const float* __restrict__ Ps,
    const int* __restrict__ E,
    float* __restrict__ sumR, float* __restrict__ sumS,
    unsigned int* __restrict__ ticket, float* __restrict__ out) {
  const int lane = threadIdx.x & 63;
  const int s    = threadIdx.x >> 6;                 // stripe id == wave id
  const int row  = blockIdx.x * 64 + lane;
  int j0 = blockIdx.y * (4 * STRIPE) + s * STRIPE;
  j0 = __builtin_amdgcn_readfirstlane(j0);           // prove wave-uniform -> s_load

  const float Ti = T[row];
  float sr = 0.0f, ss = 0.0f;
#pragma unroll 16
  for (int j = j0; j < j0 + STRIPE; ++j) {
    float4 p = pack[j];            // wave-uniform -> s_load_dwordx4 (scalar pipe)
    bool gt = (p.x > Ti);
    sr += gt ? p.y : 0.0f;         // risk: T[j] > T[i]
    ss += gt ? 0.0f : p.z;         // surv complement: T[j] <= T[i], E[j]
  }
  // complement included the diagonal (T[row]==T[row]); remove it exactly.
  if (row >= j0 && row < j0 + STRIPE) ss -= pack[row].z;

  // reduce the 4 stripes per row in LDS, one atomic pair per row per block
  __shared__ float shR[4][64];
  __shared__ float shS[4][64];
  shR[s][lane] = sr;
  shS[s][lane] = ss;
  __syncthreads();
  if (s == 0) {
    float r2 = shR[0][lane] + shR[1][lane] + shR[2][lane] + shR[3][lane];
    float s2 = shS[0][lane] + shS[1][lane] + shS[2][lane] + shS[3][lane];
    atomicAdd(&sumR[row], r2);
    atomicAdd(&sumS[row], s2);
  }
  __threadfence();
  __syncthreads();

  // last-block finalize (fence+ticket pattern; device-scope atomics)
  __shared__ unsigned int my_ticket;
  if (threadIdx.x == 0) my_ticket = atomicAdd(ticket, 1u);
  __syncthreads();
  if (my_ticket != (unsigned int)(GX * GY - 1)) return;

  float nr = 0.0f, dr = 0.0f, ns = 0.0f, nds = 0.0f;
  for (int i = threadIdx.x; i < NN; i += 256) {
    float srv = atomicAdd(&sumR[i], 0.0f);   // coherent read (cross-XCD safe)
    float ssv = atomicAdd(&sumS[i], 0.0f);
    float er = (E[i] != 0 && srv > 0.0f) ? 1.0f : 0.0f;
    float es = (ssv > 0.0f) ? 1.0f : 0.0f;
    nr  += er * (Pr[i] - logf(srv + EPSF));
    dr  += er;
    ns  += es * (Ps[i] - logf(ssv + EPSF));
    nds += es;
  }
  for (int off = 32; off > 0; off >>= 1) {
    nr  += __shfl_down(nr,  off);
    dr  += __shfl_down(dr,  off);
    ns  += __shfl_down(ns,  off);
    nds += __shfl_down(nds, off);
  }
  __shared__ float fin[4][4];
  int wid = threadIdx.x >> 6;
  if (lane == 0) {
    fin[0][wid] = nr; fin[1][wid] = dr; fin[2][wid] = ns; fin[3][wid] = nds;
  }
  __syncthreads();
  if (threadIdx.x == 0) {
    float NR = fin[0][0] + fin[0][1] + fin[0][2] + fin[0][3];
    float DR = fin[1][0] + fin[1][1] + fin[1][2] + fin[1][3];
    float NS = fin[2][0] + fin[2][1] + fin[2][2] + fin[2][3];
    float DS = fin[3][0] + fin[3][1] + fin[3][2] + fin[3][3];
    out[0] = -NR / DR;
    out[1] = -NS / DS;
  }
}

extern "C" void kernel_launch(void* const* d_in, const int* in_sizes, int n_in,
                              void* d_out, int out_size, void* d_ws, size_t ws_size,
                              hipStream_t stream) {
  const float* Pr = (const float*)d_in[0];
  const float* Ps = (const float*)d_in[1];
  const float* T  = (const float*)d_in[2];
  const int*   E  = (const int*)d_in[3];
  float* out = (float*)d_out;

  char* ws = (char*)d_ws;
  float4* pack = (float4*)ws;
  float*  sumR = (float*)(ws + (size_t)NN * sizeof(float4));
  float*  sumS = sumR + NN;
  unsigned int* ticket = (unsigned int*)(sumS + NN);

  ds_prep<<<NN / 256, 256, 0, stream>>>(Pr, Ps, T, E, pack, sumR, sumS, ticket);
  ds_main<<<dim3(GX, GY), 256, 0, stream>>>(T, pack, Pr, Ps, E, sumR, sumS, ticket, out);
}

// Round 3
// 76.703 us; speedup vs baseline: 2.5959x; 2.5959x over previous
//
#include <hip/hip_runtime.h>
#include <math.h>

#define NN 8192
#define EPSF 1e-6f
#define R 8                 // rows per block
#define GX (NN / R)         // 1024 blocks

// ws layout:
//   pack[NN]  : float4 {T[j], exp(Pr[j]), E[j]*exp(Ps[j]), 0}   (131072 B)
//   sumR[NN]  : float                                            (32768 B)
//   sumS[NN]  : float                                            (32768 B)

__global__ __launch_bounds__(256) void ds_prep(
    const float* __restrict__ Pr, const float* __restrict__ Ps,
    const float* __restrict__ T,  const int* __restrict__ E,
    float4* __restrict__ pack) {
  int i = blockIdx.x * 256 + threadIdx.x;
  float t  = T[i];
  float er = __expf(Pr[i]);
  float es = E[i] ? __expf(Ps[i]) : 0.0f;
  pack[i] = make_float4(t, er, es, 0.0f);
}

// j-parallel, row-broadcast main pass. Block b owns rows [b*R, b*R+R) and
// streams ALL j with lane-coalesced float4 loads (VMEM pipe, not scalar).
// Each block produces the COMPLETE sums for its rows -> plain stores.
__global__ __launch_bounds__(256) void ds_main(
    const float* __restrict__ T, const float4* __restrict__ pack,
    float* __restrict__ sumR, float* __restrict__ sumS) {
  const int row0 = blockIdx.x * R;
  const int tid  = threadIdx.x;

  float Ti[R];
#pragma unroll
  for (int r = 0; r < R; ++r) Ti[r] = T[row0 + r];   // block-uniform -> SGPR

  float sr[R], ss[R];
#pragma unroll
  for (int r = 0; r < R; ++r) { sr[r] = 0.0f; ss[r] = 0.0f; }

  // 8 outer iterations; 4 coalesced dwordx4 loads in flight per thread.
  for (int k = 0; k < NN; k += 256 * 4) {
    float4 p0 = pack[k + tid];
    float4 p1 = pack[k + 256 + tid];
    float4 p2 = pack[k + 512 + tid];
    float4 p3 = pack[k + 768 + tid];
#pragma unroll
    for (int r = 0; r < R; ++r) {
      bool g0 = p0.x > Ti[r];
      sr[r] += g0 ? p0.y : 0.0f;  ss[r] += g0 ? 0.0f : p0.z;
      bool g1 = p1.x > Ti[r];
      sr[r] += g1 ? p1.y : 0.0f;  ss[r] += g1 ? 0.0f : p1.z;
      bool g2 = p2.x > Ti[r];
      sr[r] += g2 ? p2.y : 0.0f;  ss[r] += g2 ? 0.0f : p2.z;
      bool g3 = p3.x > Ti[r];
      sr[r] += g3 ? p3.y : 0.0f;  ss[r] += g3 ? 0.0f : p3.z;
    }
  }

  // reduce 2R accumulators: wave shuffle, then LDS across the 4 waves
#pragma unroll
  for (int r = 0; r < R; ++r) {
    for (int off = 32; off > 0; off >>= 1) {
      sr[r] += __shfl_down(sr[r], off);
      ss[r] += __shfl_down(ss[r], off);
    }
  }
  __shared__ float sh[4][2 * R];
  const int wid = tid >> 6, lane = tid & 63;
  if (lane == 0) {
#pragma unroll
    for (int r = 0; r < R; ++r) { sh[wid][r] = sr[r]; sh[wid][R + r] = ss[r]; }
  }
  __syncthreads();
  if (tid < 2 * R) {
    float v = sh[0][tid] + sh[1][tid] + sh[2][tid] + sh[3][tid];
    if (tid < R) {
      sumR[row0 + tid] = v;
    } else {
      int r = tid - R;
      // complement (T[j] <= T[i]) included the diagonal j==i; remove exactly.
      sumS[row0 + r] = v - pack[row0 + r].z;
    }
  }
}

__global__ __launch_bounds__(1024) void ds_finalize(
    const float* __restrict__ Pr, const float* __restrict__ Ps,
    const int* __restrict__ E,
    const float* __restrict__ sumR, const float* __restrict__ sumS,
    float* __restrict__ out) {
  float nr = 0.0f, dr = 0.0f, ns = 0.0f, ds = 0.0f;
  for (int i = threadIdx.x; i < NN; i += 1024) {
    float srv = sumR[i];
    float ssv = sumS[i];
    float er = (E[i] != 0 && srv > 0.0f) ? 1.0f : 0.0f;
    float es = (ssv > 0.0f) ? 1.0f : 0.0f;
    nr += er * (Pr[i] - logf(srv + EPSF));
    dr += er;
    ns += es * (Ps[i] - logf(ssv + EPSF));
    ds += es;
  }
  for (int off = 32; off > 0; off >>= 1) {
    nr += __shfl_down(nr, off);
    dr += __shfl_down(dr, off);
    ns += __shfl_down(ns, off);
    ds += __shfl_down(ds, off);
  }
  __shared__ float sh[4][16];
  int wid  = threadIdx.x >> 6;
  int lane = threadIdx.x & 63;
  if (lane == 0) {
    sh[0][wid] = nr; sh[1][wid] = dr; sh[2][wid] = ns; sh[3][wid] = ds;
  }
  __syncthreads();
  if (threadIdx.x == 0) {
    float NR = 0, DR = 0, NS = 0, DS = 0;
#pragma unroll
    for (int w = 0; w < 16; ++w) {
      NR += sh[0][w]; DR += sh[1][w]; NS += sh[2][w]; DS += sh[3][w];
    }
    out[0] = -NR / DR;
    out[1] = -NS / DS;
  }
}

extern "C" void kernel_launch(void* const* d_in, const int* in_sizes, int n_in,
                              void* d_out, int out_size, void* d_ws, size_t ws_size,
                              hipStream_t stream) {
  const float* Pr = (const float*)d_in[0];
  const float* Ps = (const float*)d_in[1];
  const float* T  = (const float*)d_in[2];
  const int*   E  = (const int*)d_in[3];
  float* out = (float*)d_out;

  char* ws = (char*)d_ws;
  float4* pack = (float4*)ws;
  float*  sumR = (float*)(ws + (size_t)NN * sizeof(float4));
  float*  sumS = sumR + NN;

  ds_prep<<<NN / 256, 256, 0, stream>>>(Pr, Ps, T, E, pack);
  ds_main<<<GX, 256, 0, stream>>>(T, pack, sumR, sumS);
  ds_finalize<<<1, 1024, 0, stream>>>(Pr, Ps, E, sumR, sumS, out);
}